// Round 4
// baseline (66.273 us; speedup 1.0000x reference)
//
#include <hip/hip_runtime.h>
#include <math.h>

#define NN 8192
#define HH 128
#define LRELU_ALPHA 0.2f
#define R_ROWS 152          // rows with t_i possibly nonzero in f32 (i >= 8043), padded
#define I0 (NN - R_ROWS)    // 8040
#define FBLK 128            // k_front blocks
#define FROWS (NN / FBLK)   // 64 rows per front block

// ---------- K1: u = W@a (redundant per block) then f1/f2 for 64 rows ----------
__global__ __launch_bounds__(512) void k_front(const float* __restrict__ inp,
                                               const float* __restrict__ W,
                                               const float* __restrict__ a,
                                               float* __restrict__ f1,
                                               float* __restrict__ f2,
                                               unsigned* __restrict__ counter) {
    if (blockIdx.x == 0 && threadIdx.x == 0) *counter = 0u;  // reset K3's flag

    __shared__ float u1s[HH], u2s[HH];
    const int tid = threadIdx.x, wave = tid >> 6, lane = tid & 63;

    float2 av1 = ((const float2*)a)[lane];
    float2 av2 = ((const float2*)(a + HH))[lane];
    for (int k = wave; k < HH; k += 8) {
        float2 x = ((const float2*)(W + (size_t)k * HH))[lane];
        float p1 = x.x * av1.x + x.y * av1.y;
        float p2 = x.x * av2.x + x.y * av2.y;
        for (int off = 32; off; off >>= 1) {
            p1 += __shfl_down(p1, off);
            p2 += __shfl_down(p2, off);
        }
        if (lane == 0) { u1s[k] = p1; u2s[k] = p2; }
    }
    __syncthreads();

    float2 uv1 = ((const float2*)u1s)[lane];
    float2 uv2 = ((const float2*)u2s)[lane];
    int r0 = blockIdx.x * FROWS;
    for (int rr = wave; rr < FROWS; rr += 8) {
        int r = r0 + rr;
        float2 x = ((const float2*)(inp + (size_t)r * HH))[lane];
        float p1 = x.x * uv1.x + x.y * uv1.y;
        float p2 = x.x * uv2.x + x.y * uv2.y;
        for (int off = 32; off; off >>= 1) {
            p1 += __shfl_down(p1, off);
            p2 += __shfl_down(p2, off);
        }
        if (lane == 0) { f1[r] = p1; f2[r] = p2; }
    }
}

// ---------- K2: per-row softmax, one A pass, scores in registers --------------
__global__ __launch_bounds__(512) void k_row(const int* __restrict__ A,
                                             const float* __restrict__ f1,
                                             const float* __restrict__ f2,
                                             float* __restrict__ wrow) {
    const int ii = blockIdx.x;
    const int i  = I0 + ii;
    const int tid = threadIdx.x, wave = tid >> 6, lane = tid & 63;
    __shared__ float red[8];

    const int4*   arow = (const int4*)(A + (size_t)i * NN);
    const float4* f2v  = (const float4*)f2;
    const float f1i = f1[i];

    float sv[16];
    float m = -INFINITY;
    #pragma unroll
    for (int it = 0; it < 4; ++it) {
        int t = it * 512 + tid;
        int4   av = arow[t];
        float4 fv = f2v[t];
        int j0 = 4 * t;
        float x;
        x = f1i + fv.x; x = x > 0.f ? x : LRELU_ALPHA * x;
        sv[4*it+0] = ((av.x > 0) || (j0 + 0 == i)) ? x : -INFINITY;
        x = f1i + fv.y; x = x > 0.f ? x : LRELU_ALPHA * x;
        sv[4*it+1] = ((av.y > 0) || (j0 + 1 == i)) ? x : -INFINITY;
        x = f1i + fv.z; x = x > 0.f ? x : LRELU_ALPHA * x;
        sv[4*it+2] = ((av.z > 0) || (j0 + 2 == i)) ? x : -INFINITY;
        x = f1i + fv.w; x = x > 0.f ? x : LRELU_ALPHA * x;
        sv[4*it+3] = ((av.w > 0) || (j0 + 3 == i)) ? x : -INFINITY;
        m = fmaxf(m, fmaxf(fmaxf(sv[4*it], sv[4*it+1]), fmaxf(sv[4*it+2], sv[4*it+3])));
    }
    for (int off = 32; off; off >>= 1) m = fmaxf(m, __shfl_xor(m, off));
    if (lane == 0) red[wave] = m;
    __syncthreads();
    float mm = red[0];
    #pragma unroll
    for (int w = 1; w < 8; w++) mm = fmaxf(mm, red[w]);
    __syncthreads();

    float z = 0.f;
    #pragma unroll
    for (int q = 0; q < 16; q++) {
        float e = __expf(sv[q] - mm);
        sv[q] = e;
        z += e;
    }
    for (int off = 32; off; off >>= 1) z += __shfl_xor(z, off);
    if (lane == 0) red[wave] = z;
    __syncthreads();
    float zz = red[0];
    #pragma unroll
    for (int w = 1; w < 8; w++) zz += red[w];

    float ci = exp2f((float)(i - NN)) / zz;   // normalized t_i / Z_i
    float4* wout = (float4*)(wrow + (size_t)ii * NN);
    #pragma unroll
    for (int it = 0; it < 4; ++it) {
        int t = it * 512 + tid;
        float4 ev;
        ev.x = sv[4*it+0] * ci;
        ev.y = sv[4*it+1] * ci;
        ev.z = sv[4*it+2] * ci;
        ev.w = sv[4*it+3] * ci;
        wout[t] = ev;
    }
}

// ---------- K3: w_j reduce + weighted inp sum; last block: v@W + ELU ----------
__global__ __launch_bounds__(256) void k_tail(const float* __restrict__ inp,
                                              const float* __restrict__ W,
                                              const float* __restrict__ wrow,
                                              float* __restrict__ vpart,
                                              unsigned* __restrict__ counter,
                                              float* __restrict__ out) {
    const int b = blockIdx.x, jbase = b * 64, tid = threadIdx.x;
    __shared__ float red[256];
    __shared__ float wj[64];
    __shared__ float vfin[128];
    __shared__ unsigned sOld;

    // step 1: w_j for this block's 64 columns
    int jj = tid & 63, grp = tid >> 6;
    float acc = 0.f;
    for (int ii = grp; ii < R_ROWS; ii += 4)
        acc += wrow[(size_t)ii * NN + jbase + jj];
    red[tid] = acc;
    __syncthreads();
    if (tid < 64) wj[tid] = red[tid] + red[64 + tid] + red[128 + tid] + red[192 + tid];
    __syncthreads();

    // step 2: weighted sum of inp rows
    int k = tid & 127, half = tid >> 7;
    float v = 0.f;
    for (int j2 = half; j2 < 64; j2 += 2)
        v += wj[j2] * inp[(size_t)(jbase + j2) * HH + k];
    red[tid] = v;
    __syncthreads();
    if (half == 0) vpart[(size_t)b * HH + k] = red[k] + red[128 + k];

    // completion: last block does the final reduction + v@W + ELU
    __threadfence();
    if (tid == 0) sOld = atomicAdd(counter, 1u);
    __syncthreads();
    if (sOld == 127u) {
        __threadfence();
        float accv = 0.f;
        for (int bb = half; bb < 128; bb += 2)
            accv += vpart[(size_t)bb * HH + k];
        red[tid] = accv;
        __syncthreads();
        if (tid < 128) vfin[tid] = red[tid] + red[128 + tid];
        __syncthreads();
        float h = 0.f;
        for (int kk = half; kk < 128; kk += 2)
            h += vfin[kk] * W[(size_t)kk * HH + k];
        red[tid] = h;
        __syncthreads();
        if (tid < 128) {
            float ht = red[tid] + red[128 + tid];
            out[tid] = ht > 0.f ? ht : expm1f(ht);
        }
    }
}

extern "C" void kernel_launch(void* const* d_in, const int* in_sizes, int n_in,
                              void* d_out, int out_size, void* d_ws, size_t ws_size,
                              hipStream_t stream) {
    const float* inp = (const float*)d_in[0];   // [8192,128] f32
    const int*   A   = (const int*)d_in[1];     // [8192,8192] i32
    const float* W   = (const float*)d_in[2];   // [128,128] f32
    const float* a   = (const float*)d_in[3];   // [256,1] f32
    float* out = (float*)d_out;                 // [128] f32
    float* ws  = (float*)d_ws;

    // workspace layout (floats)
    float*    f1      = ws;                           // 8192
    float*    f2      = ws + NN;                      // 8192
    float*    wrow    = ws + 2 * NN;                  // 152*8192
    float*    vpart   = wrow + (size_t)R_ROWS * NN;   // 128*128
    unsigned* counter = (unsigned*)(vpart + 128 * HH);

    k_front<<<FBLK,   512, 0, stream>>>(inp, W, a, f1, f2, counter);
    k_row  <<<R_ROWS, 512, 0, stream>>>(A, f1, f2, wrow);
    k_tail <<<128,    256, 0, stream>>>(inp, W, wrow, vpart, counter, out);
}

// Round 5
// 47.723 us; speedup vs baseline: 1.3887x; 1.3887x over previous
//
#include <hip/hip_runtime.h>
#include <math.h>

#define NN 8192
#define HH 128
#define LRELU_ALPHA 0.2f
#define R_ROWS 152          // rows with t_i possibly nonzero in f32 (i >= 8043), padded
#define I0 (NN - R_ROWS)    // 8040

// ---------- K1: u1 = W @ a[:H], u2 = W @ a[H:]  (each [H]) ----------
__global__ __launch_bounds__(256) void k_prep(const float* __restrict__ W,
                                              const float* __restrict__ a,
                                              float* __restrict__ u1,
                                              float* __restrict__ u2) {
    int wave = threadIdx.x >> 6, lane = threadIdx.x & 63;
    float2 av1 = ((const float2*)a)[lane];
    float2 av2 = ((const float2*)(a + HH))[lane];
    for (int k = wave; k < HH; k += 4) {
        float2 x = ((const float2*)(W + (size_t)k * HH))[lane];
        float p1 = x.x * av1.x + x.y * av1.y;
        float p2 = x.x * av2.x + x.y * av2.y;
        for (int off = 32; off; off >>= 1) {
            p1 += __shfl_down(p1, off);
            p2 += __shfl_down(p2, off);
        }
        if (lane == 0) { u1[k] = p1; u2[k] = p2; }
    }
}

// ---------- K2: f1 = inp @ u1, f2 = inp @ u2  (each [N]) ----------
__global__ __launch_bounds__(256) void k_f(const float* __restrict__ inp,
                                           const float* __restrict__ u1,
                                           const float* __restrict__ u2,
                                           float* __restrict__ f1,
                                           float* __restrict__ f2) {
    int wave = threadIdx.x >> 6, lane = threadIdx.x & 63;
    int r = blockIdx.x * 4 + wave;
    float2 x   = ((const float2*)(inp + (size_t)r * HH))[lane];
    float2 av1 = ((const float2*)u1)[lane];
    float2 av2 = ((const float2*)u2)[lane];
    float p1 = x.x * av1.x + x.y * av1.y;
    float p2 = x.x * av2.x + x.y * av2.y;
    for (int off = 32; off; off >>= 1) {
        p1 += __shfl_down(p1, off);
        p2 += __shfl_down(p2, off);
    }
    if (lane == 0) { f1[r] = p1; f2[r] = p2; }
}

// ---------- K3: czrow[ii] = t_i / sum_validj exp(s_ij)  (no-max softmax) ------
__global__ __launch_bounds__(512) void k_zrow(const int* __restrict__ A,
                                              const float* __restrict__ f1,
                                              const float* __restrict__ f2,
                                              float* __restrict__ czrow) {
    const int ii = blockIdx.x;
    const int i  = I0 + ii;
    const int tid = threadIdx.x, wave = tid >> 6, lane = tid & 63;
    __shared__ float red[8];

    const int4*   arow = (const int4*)(A + (size_t)i * NN);
    const float4* f2v  = (const float4*)f2;
    const float f1i = f1[i];

    float z = 0.f;
    #pragma unroll
    for (int it = 0; it < 4; ++it) {
        int t = it * 512 + tid;
        int4   av = arow[t];
        float4 fv = f2v[t];
        int j0 = 4 * t;
        float x;
        x = f1i + fv.x; x = x > 0.f ? x : LRELU_ALPHA * x;
        z += ((av.x > 0) || (j0 + 0 == i)) ? __expf(x) : 0.f;
        x = f1i + fv.y; x = x > 0.f ? x : LRELU_ALPHA * x;
        z += ((av.y > 0) || (j0 + 1 == i)) ? __expf(x) : 0.f;
        x = f1i + fv.z; x = x > 0.f ? x : LRELU_ALPHA * x;
        z += ((av.z > 0) || (j0 + 2 == i)) ? __expf(x) : 0.f;
        x = f1i + fv.w; x = x > 0.f ? x : LRELU_ALPHA * x;
        z += ((av.w > 0) || (j0 + 3 == i)) ? __expf(x) : 0.f;
    }
    for (int off = 32; off; off >>= 1) z += __shfl_xor(z, off);
    if (lane == 0) red[wave] = z;
    __syncthreads();
    if (tid == 0) {
        float zz = red[0];
        #pragma unroll
        for (int w = 1; w < 8; w++) zz += red[w];
        czrow[ii] = exp2f((float)(i - NN)) / zz;   // normalized t_i / Z'_i
    }
}

// ---------- K4: per 64-j block: w_j = sum_i cz_i e^{s_ij}; vpart = sum_j w_j inp_j
__global__ __launch_bounds__(256) void k_wv(const int* __restrict__ A,
                                            const float* __restrict__ inp,
                                            const float* __restrict__ f1,
                                            const float* __restrict__ f2,
                                            const float* __restrict__ czrow,
                                            float* __restrict__ vpart) {
    const int b = blockIdx.x;          // 128 blocks
    const int jbase = b * 64;
    const int tid = threadIdx.x;
    const int jj = tid & 63, ic = tid >> 6;   // 4 i-groups x 64 j-lanes
    __shared__ float red[256];
    __shared__ float wj[64];
    __shared__ float f1s[R_ROWS], czs[R_ROWS];

    if (tid < R_ROWS) {
        f1s[tid] = f1[I0 + tid];
        czs[tid] = czrow[tid];
    }
    __syncthreads();

    const int j = jbase + jj;
    const float f2j = f2[j];

    float w = 0.f;
    #pragma unroll 2
    for (int ii = ic; ii < R_ROWS; ii += 4) {
        int av = A[(size_t)(I0 + ii) * NN + j];
        float x = f1s[ii] + f2j;
        x = x > 0.f ? x : LRELU_ALPHA * x;
        float e = __expf(x);
        w += ((av > 0) || (j == I0 + ii)) ? czs[ii] * e : 0.f;
    }
    red[ic * 64 + jj] = w;
    __syncthreads();
    if (tid < 64) wj[tid] = red[tid] + red[64 + tid] + red[128 + tid] + red[192 + tid];
    __syncthreads();

    // weighted sum of inp rows for this j-range
    int k = tid & 127, half = tid >> 7;
    float v = 0.f;
    for (int j2 = half; j2 < 64; j2 += 2)
        v += wj[j2] * inp[(size_t)(jbase + j2) * HH + k];
    red[tid] = v;
    __syncthreads();
    if (half == 0) vpart[(size_t)b * HH + k] = red[k] + red[128 + k];
}

// ---------- K5: v = sum(vpart); h_t = v @ W; out = elu(h_t) ----------
__global__ __launch_bounds__(512) void k_final(const float* __restrict__ W,
                                               const float* __restrict__ vpart,
                                               float* __restrict__ out) {
    __shared__ float red[512];
    __shared__ float v[128];
    int tid = threadIdx.x, k = tid & 127, q = tid >> 7;
    float acc = 0.f;
    for (int b = q; b < 128; b += 4) acc += vpart[(size_t)b * HH + k];
    red[q * 128 + k] = acc;
    __syncthreads();
    if (tid < 128) v[tid] = red[tid] + red[128 + tid] + red[256 + tid] + red[384 + tid];
    __syncthreads();
    float h = 0.f;
    for (int kk = q; kk < 128; kk += 4) h += v[kk] * W[(size_t)kk * HH + k];
    red[q * 128 + k] = h;
    __syncthreads();
    if (tid < 128) {
        float ht = red[tid] + red[128 + tid] + red[256 + tid] + red[384 + tid];
        out[tid] = ht > 0.f ? ht : expm1f(ht);
    }
}

extern "C" void kernel_launch(void* const* d_in, const int* in_sizes, int n_in,
                              void* d_out, int out_size, void* d_ws, size_t ws_size,
                              hipStream_t stream) {
    const float* inp = (const float*)d_in[0];   // [8192,128] f32
    const int*   A   = (const int*)d_in[1];     // [8192,8192] i32
    const float* W   = (const float*)d_in[2];   // [128,128] f32
    const float* a   = (const float*)d_in[3];   // [256,1] f32
    float* out = (float*)d_out;                 // [128] f32
    float* ws  = (float*)d_ws;

    // workspace layout (floats)
    float* u1    = ws;               // 128
    float* u2    = ws + 128;         // 128
    float* f1    = ws + 256;         // 8192
    float* f2    = ws + 256 + NN;    // 8192
    float* czrow = ws + 256 + 2*NN;  // 160 (152 used)
    float* vpart = czrow + 160;      // 128*128

    k_prep <<<1,       256, 0, stream>>>(W, a, u1, u2);
    k_f    <<<NN / 4,  256, 0, stream>>>(inp, u1, u2, f1, f2);
    k_zrow <<<R_ROWS,  512, 0, stream>>>(A, f1, f2, czrow);
    k_wv   <<<128,     256, 0, stream>>>(A, inp, f1, f2, czrow, vpart);
    k_final<<<1,       512, 0, stream>>>(W, vpart, out);
}

// Round 6
// 42.440 us; speedup vs baseline: 1.5616x; 1.1245x over previous
//
#include <hip/hip_runtime.h>
#include <math.h>

#define NN 8192
#define HH 128
#define LRELU_ALPHA 0.2f
#define R_ROWS 152          // rows with t_i possibly nonzero in f32 (i >= 8043), padded
#define I0 (NN - R_ROWS)    // 8040

// ---------- K1: u = W@a (fast redundant per block) + f1/f2 for 16 rows --------
__global__ __launch_bounds__(256) void k_front(const float* __restrict__ inp,
                                               const float* __restrict__ W,
                                               const float* __restrict__ a,
                                               float* __restrict__ f1,
                                               float* __restrict__ f2) {
    __shared__ float u1s[HH], u2s[HH];
    const int tid = threadIdx.x, wave = tid >> 6, lane = tid & 63;

    // u-compute: 2 threads per k (k = tid>>1), each half-row dot of length 64
    {
        int k = tid >> 1, half = tid & 1;
        const float4* wrow = (const float4*)(W + (size_t)k * HH + half * 64);
        const float4* a1v  = (const float4*)(a + half * 64);
        const float4* a2v  = (const float4*)(a + HH + half * 64);
        float p1 = 0.f, p2 = 0.f;
        #pragma unroll
        for (int q = 0; q < 16; q++) {
            float4 wv = wrow[q], b1 = a1v[q], b2 = a2v[q];
            p1 += wv.x * b1.x + wv.y * b1.y + wv.z * b1.z + wv.w * b1.w;
            p2 += wv.x * b2.x + wv.y * b2.y + wv.z * b2.z + wv.w * b2.w;
        }
        p1 += __shfl_xor(p1, 1);
        p2 += __shfl_xor(p2, 1);
        if (half == 0) { u1s[k] = p1; u2s[k] = p2; }
    }
    __syncthreads();

    // f-compute: 16 rows per block, 4 rows per wave
    float2 uv1 = ((const float2*)u1s)[lane];
    float2 uv2 = ((const float2*)u2s)[lane];
    int r0 = blockIdx.x * 16;
    for (int rr = wave; rr < 16; rr += 4) {
        int r = r0 + rr;
        float2 x = ((const float2*)(inp + (size_t)r * HH))[lane];
        float p1 = x.x * uv1.x + x.y * uv1.y;
        float p2 = x.x * uv2.x + x.y * uv2.y;
        for (int off = 32; off; off >>= 1) {
            p1 += __shfl_down(p1, off);
            p2 += __shfl_down(p2, off);
        }
        if (lane == 0) { f1[r] = p1; f2[r] = p2; }
    }
}

// ---------- K2: czrow[ii] = t_i / sum_validj exp(s_ij)  (no-max softmax) ------
__global__ __launch_bounds__(512) void k_zrow(const int* __restrict__ A,
                                              const float* __restrict__ f1,
                                              const float* __restrict__ f2,
                                              float* __restrict__ czrow) {
    const int ii = blockIdx.x;
    const int i  = I0 + ii;
    const int tid = threadIdx.x, wave = tid >> 6, lane = tid & 63;
    __shared__ float red[8];

    const int4*   arow = (const int4*)(A + (size_t)i * NN);
    const float4* f2v  = (const float4*)f2;
    const float f1i = f1[i];

    float z = 0.f;
    #pragma unroll
    for (int it = 0; it < 4; ++it) {
        int t = it * 512 + tid;
        int4   av = arow[t];
        float4 fv = f2v[t];
        int j0 = 4 * t;
        float x;
        x = f1i + fv.x; x = x > 0.f ? x : LRELU_ALPHA * x;
        z += ((av.x > 0) || (j0 + 0 == i)) ? __expf(x) : 0.f;
        x = f1i + fv.y; x = x > 0.f ? x : LRELU_ALPHA * x;
        z += ((av.y > 0) || (j0 + 1 == i)) ? __expf(x) : 0.f;
        x = f1i + fv.z; x = x > 0.f ? x : LRELU_ALPHA * x;
        z += ((av.z > 0) || (j0 + 2 == i)) ? __expf(x) : 0.f;
        x = f1i + fv.w; x = x > 0.f ? x : LRELU_ALPHA * x;
        z += ((av.w > 0) || (j0 + 3 == i)) ? __expf(x) : 0.f;
    }
    for (int off = 32; off; off >>= 1) z += __shfl_xor(z, off);
    if (lane == 0) red[wave] = z;
    __syncthreads();
    if (tid == 0) {
        float zz = red[0];
        #pragma unroll
        for (int w = 1; w < 8; w++) zz += red[w];
        czrow[ii] = exp2f((float)(i - NN)) / zz;   // normalized t_i / Z'_i
    }
}

// ---------- K3: per 64-j block: w_j = sum_i cz_i e^{s_ij}; vpart = sum_j w_j inp_j
__global__ __launch_bounds__(256) void k_wv(const int* __restrict__ A,
                                            const float* __restrict__ inp,
                                            const float* __restrict__ f1,
                                            const float* __restrict__ f2,
                                            const float* __restrict__ czrow,
                                            float* __restrict__ vpart) {
    const int b = blockIdx.x;          // 128 blocks
    const int jbase = b * 64;
    const int tid = threadIdx.x;
    const int jj = tid & 63, ic = tid >> 6;   // 4 i-groups x 64 j-lanes
    __shared__ float red[256];
    __shared__ float wj[64];
    __shared__ float f1s[R_ROWS], czs[R_ROWS];

    if (tid < R_ROWS) {
        f1s[tid] = f1[I0 + tid];
        czs[tid] = czrow[tid];
    }
    __syncthreads();

    const int j = jbase + jj;
    const float f2j = f2[j];

    float w = 0.f;
    #pragma unroll 2
    for (int ii = ic; ii < R_ROWS; ii += 4) {
        int av = A[(size_t)(I0 + ii) * NN + j];
        float x = f1s[ii] + f2j;
        x = x > 0.f ? x : LRELU_ALPHA * x;
        float e = __expf(x);
        w += ((av > 0) || (j == I0 + ii)) ? czs[ii] * e : 0.f;
    }
    red[ic * 64 + jj] = w;
    __syncthreads();
    if (tid < 64) wj[tid] = red[tid] + red[64 + tid] + red[128 + tid] + red[192 + tid];
    __syncthreads();

    // weighted sum of inp rows for this j-range
    int k = tid & 127, half = tid >> 7;
    float v = 0.f;
    for (int j2 = half; j2 < 64; j2 += 2)
        v += wj[j2] * inp[(size_t)(jbase + j2) * HH + k];
    red[tid] = v;
    __syncthreads();
    if (half == 0) vpart[(size_t)b * HH + k] = red[k] + red[128 + k];
}

// ---------- K4: v = sum(vpart); h_t = v @ W; out = elu(h_t) ----------
__global__ __launch_bounds__(512) void k_final(const float* __restrict__ W,
                                               const float* __restrict__ vpart,
                                               float* __restrict__ out) {
    __shared__ float red[512];
    __shared__ float v[128];
    int tid = threadIdx.x, k = tid & 127, q = tid >> 7;
    float acc = 0.f;
    for (int b = q; b < 128; b += 4) acc += vpart[(size_t)b * HH + k];
    red[q * 128 + k] = acc;
    __syncthreads();
    if (tid < 128) v[tid] = red[tid] + red[128 + tid] + red[256 + tid] + red[384 + tid];
    __syncthreads();
    float h = 0.f;
    for (int kk = q; kk < 128; kk += 4) h += v[kk] * W[(size_t)kk * HH + k];
    red[q * 128 + k] = h;
    __syncthreads();
    if (tid < 128) {
        float ht = red[tid] + red[128 + tid] + red[256 + tid] + red[384 + tid];
        out[tid] = ht > 0.f ? ht : expm1f(ht);
    }
}

extern "C" void kernel_launch(void* const* d_in, const int* in_sizes, int n_in,
                              void* d_out, int out_size, void* d_ws, size_t ws_size,
                              hipStream_t stream) {
    const float* inp = (const float*)d_in[0];   // [8192,128] f32
    const int*   A   = (const int*)d_in[1];     // [8192,8192] i32
    const float* W   = (const float*)d_in[2];   // [128,128] f32
    const float* a   = (const float*)d_in[3];   // [256,1] f32
    float* out = (float*)d_out;                 // [128] f32
    float* ws  = (float*)d_ws;

    // workspace layout (floats)
    float* f1    = ws;               // 8192
    float* f2    = ws + NN;          // 8192
    float* czrow = ws + 2 * NN;      // 160 (152 used)
    float* vpart = czrow + 160;      // 128*128

    k_front<<<NN / 16, 256, 0, stream>>>(inp, W, a, f1, f2);
    k_zrow <<<R_ROWS,  512, 0, stream>>>(A, f1, f2, czrow);
    k_wv   <<<128,     256, 0, stream>>>(A, inp, f1, f2, czrow, vpart);
    k_final<<<1,       512, 0, stream>>>(W, vpart, out);
}